// Round 5
// baseline (237.512 us; speedup 1.0000x reference)
//
#include <hip/hip_runtime.h>
#include <hip/hip_bf16.h>
#include <hip/hip_fp16.h>

// DeformableAttention on MI355X.
// prep(weights^T bf16) -> gemm_bf16(q) -> fused conv+LN+GELU+pos+sample ->
// gemm_bf16(kv) -> fused flash-attn v2 (head-paired: 2 heads/block share
// coords+gathers; K/Q direct from global/L1; wave-local P; fixed-m softmax,
// l via ones-MFMA; 4xf16 rpe entries) -> gemm_bf16(out,+bias)

#define EPS_ 1e-5f
#define ASCALE 0.17677669529663687f      // 1/sqrt(32)
#define LOG2E  1.4426950408889634f

typedef __attribute__((ext_vector_type(8))) short bf16x8;
typedef __attribute__((ext_vector_type(4))) float f32x4;

__device__ __forceinline__ short f2bf(float f) {
  union { float f; unsigned u; } v; v.f = f;
  unsigned r = (v.u + 0x7fffu + ((v.u >> 16) & 1u)) >> 16;  // RNE
  return (short)r;
}
__device__ __forceinline__ unsigned pk2bf(float a, float b) {
  union { __hip_bfloat162 h; unsigned u; } v;
  v.h = __float22bfloat162_rn(make_float2(a, b));
  return v.u;
}
__device__ __forceinline__ unsigned pkh2(float a, float b) {
  union { __half2 h; unsigned u; } v;
  v.h = __floats2half2_rn(a, b);
  return v.u;
}
__device__ __forceinline__ __half2 u2h2(unsigned u) {
  union { unsigned u; __half2 h; } v; v.u = u; return v.h;
}
__device__ __forceinline__ float exp2_fast(float x) {
  return __builtin_amdgcn_exp2f(x);
}

// ---------------------------------------------------------------------------
// Weight prep: Wkvt[n][k]=bf16(Wkv[k][n]); Woutt, Wqt likewise.
// ---------------------------------------------------------------------------
__global__ __launch_bounds__(256) void prep_weights(
    const float* __restrict__ Wkv, const float* __restrict__ Wout,
    const float* __restrict__ Wq, short* __restrict__ Wkvt,
    short* __restrict__ Woutt, short* __restrict__ Wqt)
{
  int bid = blockIdx.x, k = threadIdx.x;
  if (bid < 512) Wkvt[bid * 256 + k] = f2bf(Wkv[k * 512 + bid]);
  else if (bid < 768) { int n = bid - 512; Woutt[n * 256 + k] = f2bf(Wout[k * 256 + n]); }
  else { int n = bid - 768; Wqt[n * 256 + k] = f2bf(Wq[k * 256 + n]); }
}

// ---------------------------------------------------------------------------
// bf16 MFMA GEMM: C[M,N] = A[M,256] @ Bt[N,256]^T (+bias), with prefetch.
// ---------------------------------------------------------------------------
__global__ __launch_bounds__(256) void gemm_bf16(
    const short* __restrict__ Ab, const float* __restrict__ Af,
    const short* __restrict__ Bt,
    float* __restrict__ Cf, short* __restrict__ Cb,
    const float* __restrict__ bias, int N)
{
  __shared__ __align__(16) short As[64 * 40];
  __shared__ __align__(16) short Bs[64 * 40];
  const int t = threadIdx.x;
  const int n0 = blockIdx.x << 6, m0 = blockIdx.y << 6;
  const int wv = t >> 6, l16 = t & 15, quad = (t & 63) >> 4;
  const int row = t >> 2, koff = (t & 3) << 3;

  auto loadA = [&](int k0) -> bf16x8 {
    if (Af) {
      const float* src = &Af[(size_t)(m0 + row) * 256 + k0 + koff];
      float4 f0 = *(const float4*)src;
      float4 f1 = *(const float4*)(src + 4);
      union { unsigned u[4]; bf16x8 v; } c;
      c.u[0] = pk2bf(f0.x, f0.y); c.u[1] = pk2bf(f0.z, f0.w);
      c.u[2] = pk2bf(f1.x, f1.y); c.u[3] = pk2bf(f1.z, f1.w);
      return c.v;
    }
    return *(const bf16x8*)&Ab[(size_t)(m0 + row) * 256 + k0 + koff];
  };

  f32x4 acc[4] = {};
  bf16x8 av = loadA(0);
  bf16x8 bv = *(const bf16x8*)&Bt[(size_t)(n0 + row) * 256 + koff];
  for (int k0 = 0; k0 < 256; k0 += 32) {
    __syncthreads();  // prior-iter frag reads done before overwrite
    *(bf16x8*)&As[row * 40 + koff] = av;
    *(bf16x8*)&Bs[row * 40 + koff] = bv;
    __syncthreads();
    if (k0 + 32 < 256) {  // prefetch next chunk before MFMA section
      av = loadA(k0 + 32);
      bv = *(const bf16x8*)&Bt[(size_t)(n0 + row) * 256 + k0 + 32 + koff];
    }
    bf16x8 a = *(const bf16x8*)&As[((wv << 4) + l16) * 40 + (quad << 3)];
#pragma unroll
    for (int jt = 0; jt < 4; jt++) {
      bf16x8 bb = *(const bf16x8*)&Bs[((jt << 4) + l16) * 40 + (quad << 3)];
      acc[jt] = __builtin_amdgcn_mfma_f32_16x16x32_bf16(a, bb, acc[jt], 0, 0, 0);
    }
  }
#pragma unroll
  for (int jt = 0; jt < 4; jt++) {
#pragma unroll
    for (int r = 0; r < 4; r++) {
      int mrow = m0 + (wv << 4) + (quad << 2) + r;
      int ncol = n0 + (jt << 4) + l16;
      float v = acc[jt][r];
      if (bias) v += bias[ncol];
      if (Cf) Cf[(size_t)mrow * N + ncol] = v;
      else    Cb[(size_t)mrow * N + ncol] = f2bf(v);
    }
  }
}

// ---------------------------------------------------------------------------
// Fused: conv5x5 depthwise + LN(128) + GELU + @Woff + tanh -> pos, then
// grid_sample of this pixel's group channels -> xs (bf16). Wave per (b,g,pix).
// ---------------------------------------------------------------------------
__global__ __launch_bounds__(256) void conv_pos_sample_kernel(
    const float* __restrict__ q, const float* __restrict__ conv_w,
    const float* __restrict__ conv_b, const float* __restrict__ ln_g,
    const float* __restrict__ ln_b, const float* __restrict__ Woff,
    float* __restrict__ pos, short* __restrict__ xsb)
{
  const int p = (blockIdx.x << 2) + (threadIdx.x >> 6);
  const int lane = threadIdx.x & 63;
  const int bg = p >> 10, pix = p & 1023;
  const int hh = pix >> 5, ww = pix & 31;
  const int b = bg >> 1, g = bg & 1;
  const int c0 = lane << 1;

  float2 cb = *(const float2*)&conv_b[c0];
  float a0 = cb.x, a1 = cb.y;
  const float* w0 = conv_w + c0 * 25;
  const float* w1 = w0 + 25;
#pragma unroll
  for (int dy = 0; dy < 5; dy++) {
    int y = hh + dy - 2;
    if ((unsigned)y < 32u) {
#pragma unroll
      for (int dx = 0; dx < 5; dx++) {
        int x = ww + dx - 2;
        if ((unsigned)x < 32u) {
          float2 qv = *(const float2*)&q[(size_t)((b << 10) + (y << 5) + x) * 256 + (g << 7) + c0];
          a0 = fmaf(qv.x, w0[dy * 5 + dx], a0);
          a1 = fmaf(qv.y, w1[dy * 5 + dx], a1);
        }
      }
    }
  }
  float s1 = a0 + a1, s2 = a0 * a0 + a1 * a1;
#pragma unroll
  for (int o = 32; o; o >>= 1) { s1 += __shfl_xor(s1, o); s2 += __shfl_xor(s2, o); }
  float mu = s1 * (1.f / 128.f);
  float inv = rsqrtf(fmaf(-mu, mu, s2 * (1.f / 128.f)) + EPS_);
  float2 lg = *(const float2*)&ln_g[c0];
  float2 lb = *(const float2*)&ln_b[c0];
  float v0 = (a0 - mu) * inv * lg.x + lb.x;
  float v1 = (a1 - mu) * inv * lg.y + lb.y;
  float ge0 = 0.5f * v0 * (1.f + erff(v0 * 0.70710678118654752f));
  float ge1 = 0.5f * v1 * (1.f + erff(v1 * 0.70710678118654752f));
  float2 W0 = *(const float2*)&Woff[c0 * 2];
  float2 W1 = *(const float2*)&Woff[c0 * 2 + 2];
  float o0 = ge0 * W0.x + ge1 * W1.x;
  float o1 = ge0 * W0.y + ge1 * W1.y;
#pragma unroll
  for (int o = 32; o; o >>= 1) { o0 += __shfl_xor(o0, o); o1 += __shfl_xor(o1, o); }
  float py = tanhf(o0) * 0.0625f + ((hh + 0.5f) * 0.0625f - 1.f);
  float px = tanhf(o1) * 0.0625f + ((ww + 0.5f) * 0.0625f - 1.f);
  if (lane == 0)
    ((float2*)pos)[(bg << 10) + pix] = make_float2(py, px);

  float x = (px + 1.f) * 15.5f;
  float y = (py + 1.f) * 15.5f;
  float x0f = floorf(x), y0f = floorf(y);
  int ix0 = (int)x0f, iy0 = (int)y0f;
  float fx = x - x0f, fy = y - y0f;
  float ac0 = 0.f, ac1 = 0.f;
#pragma unroll
  for (int dy = 0; dy < 2; dy++) {
#pragma unroll
    for (int dx = 0; dx < 2; dx++) {
      int yi = iy0 + dy, xi = ix0 + dx;
      float w = (dy ? fy : 1.f - fy) * (dx ? fx : 1.f - fx);
      if ((unsigned)yi < 32u && (unsigned)xi < 32u) {
        float2 qv = *(const float2*)&q[(size_t)((b << 10) + (yi << 5) + xi) * 256 + (g << 7) + c0];
        ac0 = fmaf(w, qv.x, ac0);
        ac1 = fmaf(w, qv.y, ac1);
      }
    }
  }
  *(unsigned*)&xsb[(size_t)((b << 10) + pix) * 256 + (g << 7) + c0] = pk2bf(ac0, ac1);
}

// ---------------------------------------------------------------------------
// Fused attention v2: one block = (64-row i-tile, head-pair hp, batch).
// The 2 heads share pos -> sampling coords computed once, rpe packed as
// (h0y0,h0y1,h1y0,h1y1) f16 quads: 2 ds_read_b64 per sample serve BOTH heads.
// Q A-frags and K B-frags read straight from global (L1-resident, no LDS, no
// K-protect barrier).  P is wave-local LDS (write->read, no barrier).
// Fixed-m softmax in exp2 domain; l via ones-MFMA.
// ---------------------------------------------------------------------------
__global__ __launch_bounds__(256, 2) void attn_kernel(
    const float* __restrict__ q, const short* __restrict__ kvb,
    const float* __restrict__ pos, const float* __restrict__ rpe,
    short* __restrict__ ao)
{
  const int it = blockIdx.x, hp = blockIdx.y, b = blockIdx.z;
  const int g = hp >> 1, t = threadIdx.x;
  const int wv = t >> 6, l16 = t & 15, quad = (t & 63) >> 4;

  __shared__ __align__(16) short PL[2][64 * 72];   // P per head (wave-local rows)
  __shared__ __align__(16) short Vt[64 * 72];      // V^T, rows = hl*32+d
  __shared__ float2 posT[64];                      // (-15.5*py, -15.5*px)
  __shared__ __align__(16) uint2 rpe4[67 * 67];    // f16 quad per grid point

  // ---- stage rpe quad table (padded -2..64; OOB -> 0), *log2e
  {
    const int h0 = hp << 1;
    for (int i = t; i < 4489; i += 256) {
      int prow = i / 67, pcol = i - prow * 67;
      int ry = prow - 2, rx = pcol - 2;
      float v00 = 0.f, v01 = 0.f, v10 = 0.f, v11 = 0.f;
      if ((unsigned)rx < 63u) {
        const float* r0 = rpe + h0 * 3969 + rx;
        const float* r1 = r0 + 3969;
        if ((unsigned)ry < 63u)       { v00 = r0[ry * 63] * LOG2E;       v10 = r1[ry * 63] * LOG2E; }
        if ((unsigned)(ry + 1) < 63u) { v01 = r0[(ry + 1) * 63] * LOG2E; v11 = r1[(ry + 1) * 63] * LOG2E; }
      }
      rpe4[i] = make_uint2(pkh2(v00, v01), pkh2(v10, v11));
    }
  }

  // ---- Q A-frags from global (once per block), scaled by ASCALE*LOG2E
  const int row0 = (it << 6) + (wv << 4);
  bf16x8 aq[2];
#pragma unroll
  for (int hl = 0; hl < 2; hl++) {
    const float* src = q + (size_t)((b << 10) + row0 + l16) * 256 + (hp << 6) + (hl << 5) + (quad << 3);
    float4 f0 = *(const float4*)src;
    float4 f1 = *(const float4*)(src + 4);
    const float sc = ASCALE * LOG2E;
    union { unsigned u[4]; bf16x8 v; } c;
    c.u[0] = pk2bf(f0.x * sc, f0.y * sc); c.u[1] = pk2bf(f0.z * sc, f0.w * sc);
    c.u[2] = pk2bf(f1.x * sc, f1.y * sc); c.u[3] = pk2bf(f1.z * sc, f1.w * sc);
    aq[hl] = c.v;
  }

  // sampling coords (padded +2 origin): wave's 16 rows share one raster row
  const float ayc = 15.5f * (((row0 >> 5) + 0.5f) * 0.0625f - 1.f) + 33.f;
  float ax[4];
#pragma unroll
  for (int r = 0; r < 4; r++) {
    int ix = (row0 & 31) + (quad << 2) + r;
    ax[r] = 15.5f * ((ix + 0.5f) * 0.0625f - 1.f) + 33.f;
  }

  bf16x8 vones;
#pragma unroll
  for (int i = 0; i < 8; i++) vones[i] = (short)0x3F80;  // bf16 1.0

  f32x4 Oacc[2][2] = {};
  f32x4 lacc[2] = {};

  for (int kt = 0; kt < 16; kt++) {
    const int jb = kt << 6;
    __syncthreads();  // [b1] prior PV reads of Vt / posT done
    // ---- stage V^T (conflict-free writes: banks = const + j/2)
#pragma unroll
    for (int iter = 0; iter < 2; iter++) {
      int j = t & 63, c = (t >> 6) + (iter << 2);
      bf16x8 vv = *(const bf16x8*)&kvb[(size_t)((b << 10) + jb + j) * 512 + 256 + (hp << 6) + (c << 3)];
#pragma unroll
      for (int k2 = 0; k2 < 8; k2++) Vt[((c << 3) + k2) * 72 + j] = vv[k2];
    }
    if (t < 64) {
      float2 pp = ((const float2*)pos)[(((b << 1) + g) << 10) + jb + t];
      posT[t] = make_float2(-15.5f * pp.x, -15.5f * pp.y);
    }
    __syncthreads();  // [b2]

    // ---- QK^T: K B-frags straight from global (L1), 8 MFMA
    f32x4 S[2][4];
#pragma unroll
    for (int hl = 0; hl < 2; hl++)
#pragma unroll
      for (int jt = 0; jt < 4; jt++) {
        bf16x8 bk = *(const bf16x8*)&kvb[(size_t)((b << 10) + jb + (jt << 4) + l16) * 512 + (hp << 6) + (hl << 5) + (quad << 3)];
        f32x4 z = {};
        S[hl][jt] = __builtin_amdgcn_mfma_f32_16x16x32_bf16(aq[hl], bk, z, 0, 0, 0);
      }

    // ---- bias sample (shared coords, both heads) + p = exp2(S+bias)
    unsigned pu[2][4][2];
#pragma unroll
    for (int jt = 0; jt < 4; jt++) {
      float2 bv = posT[(jt << 4) + l16];
      float ys = ayc + bv.x;
      float y0f = floorf(ys);
      float fy = ys - y0f;
      int ybase = (int)y0f * 67;
      float pv0[4], pv1[4];
#pragma unroll
      for (int r = 0; r < 4; r++) {
        float sx = ax[r] + bv.y;
        float x0f = floorf(sx);
        float fx = sx - x0f;
        int idx = ybase + (int)x0f;
        uint2 e0 = rpe4[idx];
        uint2 e1 = rpe4[idx + 1];
        __half2 fx2 = __float2half2_rn(fx);
        __half2 ta = __hfma2(fx2, __hsub2(u2h2(e1.x), u2h2(e0.x)), u2h2(e0.x));
        __half2 tb = __hfma2(fx2, __hsub2(u2h2(e1.y), u2h2(e0.y)), u2h2(e0.y));
        float alo = __low2float(ta), ahi = __high2float(ta);
        float blo = __low2float(tb), bhi = __high2float(tb);
        float bias0 = fmaf(fy, ahi - alo, alo);
        float bias1 = fmaf(fy, bhi - blo, blo);
        pv0[r] = exp2_fast(S[0][jt][r] + bias0);
        pv1[r] = exp2_fast(S[1][jt][r] + bias1);
      }
      pu[0][jt][0] = pk2bf(pv0[0], pv0[1]); pu[0][jt][1] = pk2bf(pv0[2], pv0[3]);
      pu[1][jt][0] = pk2bf(pv1[0], pv1[1]); pu[1][jt][1] = pk2bf(pv1[2], pv1[3]);
    }

    // ---- per head: wave-local P write -> A-frag read -> PV + l (no barrier)
#pragma unroll
    for (int hl = 0; hl < 2; hl++) {
      short* PLh = PL[hl];
#pragma unroll
      for (int jt = 0; jt < 4; jt++) {
        int cb = (jt << 4) + l16;
        int rb = ((wv << 4) + (quad << 2)) * 72 + cb;
        PLh[rb]       = (short)(pu[hl][jt][0] & 0xffff);
        PLh[rb + 72]  = (short)(pu[hl][jt][0] >> 16);
        PLh[rb + 144] = (short)(pu[hl][jt][1] & 0xffff);
        PLh[rb + 216] = (short)(pu[hl][jt][1] >> 16);
      }
      bf16x8 pa0 = *(const bf16x8*)&PLh[((wv << 4) + l16) * 72 + (quad << 3)];
      bf16x8 pa1 = *(const bf16x8*)&PLh[((wv << 4) + l16) * 72 + 32 + (quad << 3)];
#pragma unroll
      for (int dt = 0; dt < 2; dt++) {
        bf16x8 vb0 = *(const bf16x8*)&Vt[((hl << 5) + (dt << 4) + l16) * 72 + (quad << 3)];
        bf16x8 vb1 = *(const bf16x8*)&Vt[((hl << 5) + (dt << 4) + l16) * 72 + 32 + (quad << 3)];
        Oacc[hl][dt] = __builtin_amdgcn_mfma_f32_16x16x32_bf16(pa0, vb0, Oacc[hl][dt], 0, 0, 0);
        Oacc[hl][dt] = __builtin_amdgcn_mfma_f32_16x16x32_bf16(pa1, vb1, Oacc[hl][dt], 0, 0, 0);
      }
      lacc[hl] = __builtin_amdgcn_mfma_f32_16x16x32_bf16(pa0, vones, lacc[hl], 0, 0, 0);
      lacc[hl] = __builtin_amdgcn_mfma_f32_16x16x32_bf16(pa1, vones, lacc[hl], 0, 0, 0);
    }
  }

  // ---- epilogue -> ao bf16
#pragma unroll
  for (int hl = 0; hl < 2; hl++)
#pragma unroll
    for (int r = 0; r < 4; r++) {
      float inv = 1.f / lacc[hl][r];
      int row = row0 + (quad << 2) + r;
#pragma unroll
      for (int dt = 0; dt < 2; dt++) {
        ao[(size_t)((b << 10) + row) * 256 + (hp << 6) + (hl << 5) + (dt << 4) + l16] =
            f2bf(Oacc[hl][dt][r] * inv);
      }
    }
}

// ---------------------------------------------------------------------------
extern "C" void kernel_launch(void* const* d_in, const int* in_sizes, int n_in,
                              void* d_out, int out_size, void* d_ws, size_t ws_size,
                              hipStream_t stream) {
  (void)in_sizes; (void)n_in; (void)out_size; (void)ws_size;
  const float* x      = (const float*)d_in[0];
  const float* Wq     = (const float*)d_in[1];
  const float* Wkv    = (const float*)d_in[2];
  const float* conv_w = (const float*)d_in[3];
  const float* conv_b = (const float*)d_in[4];
  const float* ln_g   = (const float*)d_in[5];
  const float* ln_b   = (const float*)d_in[6];
  const float* Woff   = (const float*)d_in[7];
  const float* rpe    = (const float*)d_in[8];
  const float* Wout   = (const float*)d_in[9];
  const float* bout   = (const float*)d_in[10];
  float* out = (float*)d_out;

  float* ws    = (float*)d_ws;
  float* q     = ws;                       // 2,097,152 f32
  float* pos   = ws + 2097152;             //    32,768 f32
  short* kvb   = (short*)(ws + 2129920);   // 8192*512 bf16
  short* xsb   = (short*)(ws + 4227072);   // 8192*256 bf16
  short* aob   = (short*)(ws + 5275648);   // 8192*256 bf16
  short* Wkvt  = (short*)(ws + 6324224);   // 512*256 bf16
  short* Woutt = (short*)(ws + 6389760);   // 256*256 bf16
  short* Wqt   = (short*)(ws + 6422528);   // 256*256 bf16

  prep_weights<<<1024, 256, 0, stream>>>(Wkv, Wout, Wq, Wkvt, Woutt, Wqt);
  // 1. q = x @ Wq (bf16 MFMA, f32 A staged+converted, f32 out)
  gemm_bf16<<<dim3(4, 128), 256, 0, stream>>>(nullptr, x, Wqt, q, nullptr, nullptr, 256);
  // 2+3. conv + LN + GELU + Woff + tanh -> pos, fused grid_sample -> xs
  conv_pos_sample_kernel<<<4096, 256, 0, stream>>>(q, conv_w, conv_b, ln_g, ln_b,
                                                   Woff, pos, xsb);
  // 4. kv = xs @ Wkv (bf16 MFMA, bf16 out)
  gemm_bf16<<<dim3(8, 128), 256, 0, stream>>>(xsb, nullptr, Wkvt, nullptr, kvb, nullptr, 512);
  // 5. fused attention v2 (head-paired) -> ao (bf16)
  attn_kernel<<<dim3(16, 4, 8), 256, 0, stream>>>(q, kvb, pos, rpe, aob);
  // 6. out = ao @ Wout + bout (bf16 MFMA, f32 out)
  gemm_bf16<<<dim3(4, 128), 256, 0, stream>>>(aob, nullptr, Woutt, out, nullptr, bout, 256);
}

// Round 6
// 236.756 us; speedup vs baseline: 1.0032x; 1.0032x over previous
//
#include <hip/hip_runtime.h>
#include <hip/hip_bf16.h>
#include <hip/hip_fp16.h>
#include <hip/hip_fp8.h>

// DeformableAttention on MI355X.
// prep(weights^T bf16) -> gemm_bf16(q) -> fused conv+LN+GELU+pos+sample ->
// gemm_bf16(kv) -> fused flash-attn v3 (1 head/block, grid 1024, ~30 KB LDS
// -> 4 blocks/CU; fp8 rpe quad table: 1 ds_read_b32/sample for all 4 taps;
// K/Q direct from global; wave-local P; fixed-m softmax, l via ones-MFMA)
// -> gemm_bf16(out,+bias)

#define EPS_ 1e-5f
#define ASCALE 0.17677669529663687f      // 1/sqrt(32)
#define LOG2E  1.4426950408889634f

typedef __attribute__((ext_vector_type(8))) short bf16x8;
typedef __attribute__((ext_vector_type(4))) float f32x4;

__device__ __forceinline__ short f2bf(float f) {
  union { float f; unsigned u; } v; v.f = f;
  unsigned r = (v.u + 0x7fffu + ((v.u >> 16) & 1u)) >> 16;  // RNE
  return (short)r;
}
__device__ __forceinline__ unsigned pk2bf(float a, float b) {
  union { __hip_bfloat162 h; unsigned u; } v;
  v.h = __float22bfloat162_rn(make_float2(a, b));
  return v.u;
}
__device__ __forceinline__ float exp2_fast(float x) {
  return __builtin_amdgcn_exp2f(x);
}

// ---------------------------------------------------------------------------
// Weight prep: Wkvt[n][k]=bf16(Wkv[k][n]); Woutt, Wqt likewise.
// ---------------------------------------------------------------------------
__global__ __launch_bounds__(256) void prep_weights(
    const float* __restrict__ Wkv, const float* __restrict__ Wout,
    const float* __restrict__ Wq, short* __restrict__ Wkvt,
    short* __restrict__ Woutt, short* __restrict__ Wqt)
{
  int bid = blockIdx.x, k = threadIdx.x;
  if (bid < 512) Wkvt[bid * 256 + k] = f2bf(Wkv[k * 512 + bid]);
  else if (bid < 768) { int n = bid - 512; Woutt[n * 256 + k] = f2bf(Wout[k * 256 + n]); }
  else { int n = bid - 768; Wqt[n * 256 + k] = f2bf(Wq[k * 256 + n]); }
}

// ---------------------------------------------------------------------------
// bf16 MFMA GEMM: C[M,N] = A[M,256] @ Bt[N,256]^T (+bias), with prefetch.
// ---------------------------------------------------------------------------
__global__ __launch_bounds__(256) void gemm_bf16(
    const short* __restrict__ Ab, const float* __restrict__ Af,
    const short* __restrict__ Bt,
    float* __restrict__ Cf, short* __restrict__ Cb,
    const float* __restrict__ bias, int N)
{
  __shared__ __align__(16) short As[64 * 40];
  __shared__ __align__(16) short Bs[64 * 40];
  const int t = threadIdx.x;
  const int n0 = blockIdx.x << 6, m0 = blockIdx.y << 6;
  const int wv = t >> 6, l16 = t & 15, quad = (t & 63) >> 4;
  const int row = t >> 2, koff = (t & 3) << 3;

  auto loadA = [&](int k0) -> bf16x8 {
    if (Af) {
      const float* src = &Af[(size_t)(m0 + row) * 256 + k0 + koff];
      float4 f0 = *(const float4*)src;
      float4 f1 = *(const float4*)(src + 4);
      union { unsigned u[4]; bf16x8 v; } c;
      c.u[0] = pk2bf(f0.x, f0.y); c.u[1] = pk2bf(f0.z, f0.w);
      c.u[2] = pk2bf(f1.x, f1.y); c.u[3] = pk2bf(f1.z, f1.w);
      return c.v;
    }
    return *(const bf16x8*)&Ab[(size_t)(m0 + row) * 256 + k0 + koff];
  };

  f32x4 acc[4] = {};
  bf16x8 av = loadA(0);
  bf16x8 bv = *(const bf16x8*)&Bt[(size_t)(n0 + row) * 256 + koff];
  for (int k0 = 0; k0 < 256; k0 += 32) {
    __syncthreads();  // prior-iter frag reads done before overwrite
    *(bf16x8*)&As[row * 40 + koff] = av;
    *(bf16x8*)&Bs[row * 40 + koff] = bv;
    __syncthreads();
    if (k0 + 32 < 256) {  // prefetch next chunk before MFMA section
      av = loadA(k0 + 32);
      bv = *(const bf16x8*)&Bt[(size_t)(n0 + row) * 256 + k0 + 32 + koff];
    }
    bf16x8 a = *(const bf16x8*)&As[((wv << 4) + l16) * 40 + (quad << 3)];
#pragma unroll
    for (int jt = 0; jt < 4; jt++) {
      bf16x8 bb = *(const bf16x8*)&Bs[((jt << 4) + l16) * 40 + (quad << 3)];
      acc[jt] = __builtin_amdgcn_mfma_f32_16x16x32_bf16(a, bb, acc[jt], 0, 0, 0);
    }
  }
#pragma unroll
  for (int jt = 0; jt < 4; jt++) {
#pragma unroll
    for (int r = 0; r < 4; r++) {
      int mrow = m0 + (wv << 4) + (quad << 2) + r;
      int ncol = n0 + (jt << 4) + l16;
      float v = acc[jt][r];
      if (bias) v += bias[ncol];
      if (Cf) Cf[(size_t)mrow * N + ncol] = v;
      else    Cb[(size_t)mrow * N + ncol] = f2bf(v);
    }
  }
}

// ---------------------------------------------------------------------------
// Fused: conv5x5 depthwise + LN(128) + GELU + @Woff + tanh -> pos, then
// grid_sample of this pixel's group channels -> xs (bf16). Wave per (b,g,pix).
// ---------------------------------------------------------------------------
__global__ __launch_bounds__(256) void conv_pos_sample_kernel(
    const float* __restrict__ q, const float* __restrict__ conv_w,
    const float* __restrict__ conv_b, const float* __restrict__ ln_g,
    const float* __restrict__ ln_b, const float* __restrict__ Woff,
    float* __restrict__ pos, short* __restrict__ xsb)
{
  const int p = (blockIdx.x << 2) + (threadIdx.x >> 6);
  const int lane = threadIdx.x & 63;
  const int bg = p >> 10, pix = p & 1023;
  const int hh = pix >> 5, ww = pix & 31;
  const int b = bg >> 1, g = bg & 1;
  const int c0 = lane << 1;

  float2 cb = *(const float2*)&conv_b[c0];
  float a0 = cb.x, a1 = cb.y;
  const float* w0 = conv_w + c0 * 25;
  const float* w1 = w0 + 25;
#pragma unroll
  for (int dy = 0; dy < 5; dy++) {
    int y = hh + dy - 2;
    if ((unsigned)y < 32u) {
#pragma unroll
      for (int dx = 0; dx < 5; dx++) {
        int x = ww + dx - 2;
        if ((unsigned)x < 32u) {
          float2 qv = *(const float2*)&q[(size_t)((b << 10) + (y << 5) + x) * 256 + (g << 7) + c0];
          a0 = fmaf(qv.x, w0[dy * 5 + dx], a0);
          a1 = fmaf(qv.y, w1[dy * 5 + dx], a1);
        }
      }
    }
  }
  float s1 = a0 + a1, s2 = a0 * a0 + a1 * a1;
#pragma unroll
  for (int o = 32; o; o >>= 1) { s1 += __shfl_xor(s1, o); s2 += __shfl_xor(s2, o); }
  float mu = s1 * (1.f / 128.f);
  float inv = rsqrtf(fmaf(-mu, mu, s2 * (1.f / 128.f)) + EPS_);
  float2 lg = *(const float2*)&ln_g[c0];
  float2 lb = *(const float2*)&ln_b[c0];
  float v0 = (a0 - mu) * inv * lg.x + lb.x;
  float v1 = (a1 - mu) * inv * lg.y + lb.y;
  float ge0 = 0.5f * v0 * (1.f + erff(v0 * 0.70710678118654752f));
  float ge1 = 0.5f * v1 * (1.f + erff(v1 * 0.70710678118654752f));
  float2 W0 = *(const float2*)&Woff[c0 * 2];
  float2 W1 = *(const float2*)&Woff[c0 * 2 + 2];
  float o0 = ge0 * W0.x + ge1 * W1.x;
  float o1 = ge0 * W0.y + ge1 * W1.y;
#pragma unroll
  for (int o = 32; o; o >>= 1) { o0 += __shfl_xor(o0, o); o1 += __shfl_xor(o1, o); }
  float py = tanhf(o0) * 0.0625f + ((hh + 0.5f) * 0.0625f - 1.f);
  float px = tanhf(o1) * 0.0625f + ((ww + 0.5f) * 0.0625f - 1.f);
  if (lane == 0)
    ((float2*)pos)[(bg << 10) + pix] = make_float2(py, px);

  float x = (px + 1.f) * 15.5f;
  float y = (py + 1.f) * 15.5f;
  float x0f = floorf(x), y0f = floorf(y);
  int ix0 = (int)x0f, iy0 = (int)y0f;
  float fx = x - x0f, fy = y - y0f;
  float ac0 = 0.f, ac1 = 0.f;
#pragma unroll
  for (int dy = 0; dy < 2; dy++) {
#pragma unroll
    for (int dx = 0; dx < 2; dx++) {
      int yi = iy0 + dy, xi = ix0 + dx;
      float w = (dy ? fy : 1.f - fy) * (dx ? fx : 1.f - fx);
      if ((unsigned)yi < 32u && (unsigned)xi < 32u) {
        float2 qv = *(const float2*)&q[(size_t)((b << 10) + (yi << 5) + xi) * 256 + (g << 7) + c0];
        ac0 = fmaf(w, qv.x, ac0);
        ac1 = fmaf(w, qv.y, ac1);
      }
    }
  }
  *(unsigned*)&xsb[(size_t)((b << 10) + pix) * 256 + (g << 7) + c0] = pk2bf(ac0, ac1);
}

// ---------------------------------------------------------------------------
// Fused attention v3: one block = (64-row i-tile, head, batch), grid 1024.
// LDS ~30 KB -> 4 blocks/CU (16 waves).  rpe staged as fp8-e4m3 quads
// (g00,g10,g01,g11)*log2e over the reachable 64x64 window: ONE ds_read_b32
// per sample yields all 4 bilinear taps (decode = 2 HW fp8x2->f32 cvts).
// K B-frags / Q A-frags direct from global (L1-hot).  P wave-local in LDS
// (no barrier between write and read).  Fixed-m softmax in exp2 domain;
// row-sum l via ones-MFMA.
// ---------------------------------------------------------------------------
__global__ __launch_bounds__(256, 4) void attn_kernel(
    const float* __restrict__ q, const short* __restrict__ kvb,
    const float* __restrict__ pos, const float* __restrict__ rpe,
    short* __restrict__ ao)
{
  const int it = blockIdx.x, h = blockIdx.y, b = blockIdx.z;
  const int g = h >> 2, t = threadIdx.x;
  const int wv = t >> 6, l16 = t & 15, quad = (t & 63) >> 4;

  __shared__ __align__(16) short PL[64 * 72];     // P (wave-local rows)
  __shared__ __align__(16) short Vt[32 * 68];     // V^T [d][j]
  __shared__ float2 posT[64];                     // (-15.5*py, -15.5*px)
  __shared__ __align__(16) unsigned rpe8[64 * 64];  // fp8 quad per point

  // ---- stage fp8 rpe quad table over the reachable window.
  // Sample coords use origin +31: ys = 31 + 15.5*(ref_i - py_j) in (0,62),
  // so y0,x0 in [0,61] and taps y0+1,x0+1 <= 62: 64x64 covers everything.
  // Table point (ty,tx) maps directly to rpe grid (ty,tx); rows/cols 63 pad 0.
  {
    const float* rp = rpe + h * 3969;
    for (int i = t; i < 4096; i += 256) {
      int ty = i >> 6, tx = i & 63;
      float v00 = 0.f, v10 = 0.f, v01 = 0.f, v11 = 0.f;
      if (tx <= 62) {
        if (ty <= 62) v00 = rp[ty * 63 + tx] * LOG2E;
        if (ty <= 61) v10 = rp[(ty + 1) * 63 + tx] * LOG2E;
      }
      if (tx <= 61) {
        if (ty <= 62) v01 = rp[ty * 63 + tx + 1] * LOG2E;
        if (ty <= 61) v11 = rp[(ty + 1) * 63 + tx + 1] * LOG2E;
      }
      __hip_fp8x2_e4m3 elo(make_float2(v00, v10));   // y-pair at x0
      __hip_fp8x2_e4m3 ehi(make_float2(v01, v11));   // y-pair at x0+1
      rpe8[i] = (unsigned)(unsigned short)elo.__x |
                ((unsigned)(unsigned short)ehi.__x << 16);
    }
  }

  // ---- Q A-frag from global (once), scaled by ASCALE*LOG2E
  const int row0 = (it << 6) + (wv << 4);
  bf16x8 aq;
  {
    const float* src = q + (size_t)((b << 10) + row0 + l16) * 256 + (h << 5) + (quad << 3);
    float4 f0 = *(const float4*)src;
    float4 f1 = *(const float4*)(src + 4);
    const float sc = ASCALE * LOG2E;
    union { unsigned u[4]; bf16x8 v; } c;
    c.u[0] = pk2bf(f0.x * sc, f0.y * sc); c.u[1] = pk2bf(f0.z * sc, f0.w * sc);
    c.u[2] = pk2bf(f1.x * sc, f1.y * sc); c.u[3] = pk2bf(f1.z * sc, f1.w * sc);
    aq = c.v;
  }

  // sampling coords (origin +31): wave's 16 rows share one raster row
  const float ayc = 15.5f * (((row0 >> 5) + 0.5f) * 0.0625f - 1.f) + 31.f;
  float ax[4];
#pragma unroll
  for (int r = 0; r < 4; r++) {
    int ix = (row0 & 31) + (quad << 2) + r;
    ax[r] = 15.5f * ((ix + 0.5f) * 0.0625f - 1.f) + 31.f;
  }

  bf16x8 vones;
#pragma unroll
  for (int i = 0; i < 8; i++) vones[i] = (short)0x3F80;  // bf16 1.0

  f32x4 Oacc[2] = {};
  f32x4 lacc = {};

  for (int kt = 0; kt < 16; kt++) {
    const int jb = kt << 6;
    __syncthreads();  // [b1] prior PV reads of Vt/posT done
    // ---- stage V^T: thread (j = t&63, c = t>>6) -> d = c*8..c*8+7
    {
      int j = t & 63, c = t >> 6;
      bf16x8 vv = *(const bf16x8*)&kvb[(size_t)((b << 10) + jb + j) * 512 + 256 + (h << 5) + (c << 3)];
#pragma unroll
      for (int k2 = 0; k2 < 8; k2++) Vt[((c << 3) + k2) * 68 + j] = vv[k2];
    }
    if (t < 64) {
      float2 pp = ((const float2*)pos)[(((b << 1) + g) << 10) + jb + t];
      posT[t] = make_float2(-15.5f * pp.x, -15.5f * pp.y);
    }
    __syncthreads();  // [b2]

    // ---- QK^T: K B-frags straight from global (L1), 4 MFMA
    f32x4 S[4];
#pragma unroll
    for (int jt = 0; jt < 4; jt++) {
      bf16x8 bk = *(const bf16x8*)&kvb[(size_t)((b << 10) + jb + (jt << 4) + l16) * 512 + (h << 5) + (quad << 3)];
      f32x4 z = {};
      S[jt] = __builtin_amdgcn_mfma_f32_16x16x32_bf16(aq, bk, z, 0, 0, 0);
    }

    // ---- bias sample (1 b32 gather/sample) + p = exp2(S+bias)
    unsigned pu[4][2];
#pragma unroll
    for (int jt = 0; jt < 4; jt++) {
      float2 bv = posT[(jt << 4) + l16];
      float ys = ayc + bv.x;
      float y0f = floorf(ys);
      float fy = ys - y0f;
      int ybase = (int)y0f << 6;
      float pv[4];
#pragma unroll
      for (int r = 0; r < 4; r++) {
        float sx = ax[r] + bv.y;
        float x0f = floorf(sx);
        float fx = sx - x0f;
        unsigned u = rpe8[ybase + (int)x0f];
        __hip_fp8x2_e4m3 plo, phi;
        plo.__x = (__hip_fp8x2_storage_t)(unsigned short)(u & 0xffffu);
        phi.__x = (__hip_fp8x2_storage_t)(unsigned short)(u >> 16);
        float2 ga = (float2)plo;   // (g00, g10)
        float2 gb = (float2)phi;   // (g01, g11)
        float h0 = fmaf(fx, gb.x - ga.x, ga.x);
        float h1 = fmaf(fx, gb.y - ga.y, ga.y);
        float bias = fmaf(fy, h1 - h0, h0);
        pv[r] = exp2_fast(S[jt][r] + bias);
      }
      pu[jt][0] = pk2bf(pv[0], pv[1]);
      pu[jt][1] = pk2bf(pv[2], pv[3]);
    }

    // ---- wave-local P write -> A-frag read -> PV + l (no barrier)
#pragma unroll
    for (int jt = 0; jt < 4; jt++) {
      int cb = (jt << 4) + l16;
      int rb = ((wv << 4) + (quad << 2)) * 72 + cb;
      PL[rb]       = (short)(pu[jt][0] & 0xffff);
      PL[rb + 72]  = (short)(pu[jt][0] >> 16);
      PL[rb + 144] = (short)(pu[jt][1] & 0xffff);
      PL[rb + 216] = (short)(pu[jt][1] >> 16);
    }
    bf16x8 pa0 = *(const bf16x8*)&PL[((wv << 4) + l16) * 72 + (quad << 3)];
    bf16x8 pa1 = *(const bf16x8*)&PL[((wv << 4) + l16) * 72 + 32 + (quad << 3)];
#pragma unroll
    for (int dt = 0; dt < 2; dt++) {
      bf16x8 vb0 = *(const bf16x8*)&Vt[((dt << 4) + l16) * 68 + (quad << 3)];
      bf16x8 vb1 = *(const bf16x8*)&Vt[((dt << 4) + l16) * 68 + 32 + (quad << 3)];
      Oacc[dt] = __builtin_amdgcn_mfma_f32_16x16x32_bf16(pa0, vb0, Oacc[dt], 0, 0, 0);
      Oacc[dt] = __builtin_amdgcn_mfma_f32_16x16x32_bf16(pa1, vb1, Oacc[dt], 0, 0, 0);
    }
    lacc = __builtin_amdgcn_mfma_f32_16x16x32_bf16(pa0, vones, lacc, 0, 0, 0);
    lacc = __builtin_amdgcn_mfma_f32_16x16x32_bf16(pa1, vones, lacc, 0, 0, 0);
  }

  // ---- epilogue -> ao bf16
#pragma unroll
  for (int r = 0; r < 4; r++) {
    float inv = 1.f / lacc[r];
    int row = row0 + (quad << 2) + r;
#pragma unroll
    for (int dt = 0; dt < 2; dt++) {
      ao[(size_t)((b << 10) + row) * 256 + (h << 5) + (dt << 4) + l16] =
          f2bf(Oacc[dt][r] * inv);
    }
  }
}

// ---------------------------------------------------------------------------
extern "C" void kernel_launch(void* const* d_in, const int* in_sizes, int n_in,
                              void* d_out, int out_size, void* d_ws, size_t ws_size,
                              hipStream_t stream) {
  (void)in_sizes; (void)n_in; (void)out_size; (void)ws_size;
  const float* x      = (const float*)d_in[0];
  const float* Wq     = (const float*)d_in[1];
  const float* Wkv    = (const float*)d_in[2];
  const float* conv_w = (const float*)d_in[3];
  const float* conv_b = (const float*)d_in[4];
  const float* ln_g   = (const float*)d_in[5];
  const float* ln_b   = (const float*)d_in[6];
  const float* Woff   = (const float*)d_in[7];
  const float* rpe    = (const float*)d_in[8];
  const float* Wout   = (const float*)d_in[9];
  const float* bout   = (const float*)d_in[10];
  float* out = (float*)d_out;

  float* ws    = (float*)d_ws;
  float* q     = ws;                       // 2,097,152 f32
  float* pos   = ws + 2097152;             //    32,768 f32
  short* kvb   = (short*)(ws + 2129920);   // 8192*512 bf16
  short* xsb   = (short*)(ws + 4227072);   // 8192*256 bf16
  short* aob   = (short*)(ws + 5275648);   // 8192*256 bf16
  short* Wkvt  = (short*)(ws + 6324224);   // 512*256 bf16
  short* Woutt = (short*)(ws + 6389760);   // 256*256 bf16
  short* Wqt   = (short*)(ws + 6422528);   // 256*256 bf16

  prep_weights<<<1024, 256, 0, stream>>>(Wkv, Wout, Wq, Wkvt, Woutt, Wqt);
  // 1. q = x @ Wq (bf16 MFMA, f32 A staged+converted, f32 out)
  gemm_bf16<<<dim3(4, 128), 256, 0, stream>>>(nullptr, x, Wqt, q, nullptr, nullptr, 256);
  // 2+3. conv + LN + GELU + Woff + tanh -> pos, fused grid_sample -> xs
  conv_pos_sample_kernel<<<4096, 256, 0, stream>>>(q, conv_w, conv_b, ln_g, ln_b,
                                                   Woff, pos, xsb);
  // 4. kv = xs @ Wkv (bf16 MFMA, bf16 out)
  gemm_bf16<<<dim3(8, 128), 256, 0, stream>>>(xsb, nullptr, Wkvt, nullptr, kvb, nullptr, 512);
  // 5. fused attention v3 (1 head/block, high occupancy) -> ao (bf16)
  attn_kernel<<<dim3(16, 8, 8), 256, 0, stream>>>(q, kvb, pos, rpe, aob);
  // 6. out = ao @ Wout + bout (bf16 MFMA, f32 out)
  gemm_bf16<<<dim3(4, 128), 256, 0, stream>>>(aob, nullptr, Woutt, out, nullptr, bout, 256);
}